// Round 1
// baseline (6211.676 us; speedup 1.0000x reference)
//
#include <hip/hip_runtime.h>
#include <hip/hip_bf16.h>
#include <math.h>

// Graph problem: 2 iterations of {row-L2-normalize -> scatter-add over edges ->
// 2x2 matmul + ReLU}, then sigmoid(x @ final_weight).
// N = 1M nodes, 2 features; E = 32M edges.

#define EPS 1e-15f

// K1: normalize the (immutable) input x into A
__global__ void norm_input_kernel(const float2* __restrict__ x,
                                  float2* __restrict__ A, int N) {
    int n = blockIdx.x * blockDim.x + threadIdx.x;
    if (n >= N) return;
    float2 v = x[n];
    float nm = sqrtf(v.x * v.x + v.y * v.y);
    float inv = 1.0f / (nm + EPS);
    A[n] = make_float2(v.x * inv, v.y * inv);
}

// K2: scatter-add xn[src] into B[dst] (aggr='add')
__global__ void scatter_kernel(const int* __restrict__ src,
                               const int* __restrict__ dst,
                               const float2* __restrict__ A,
                               float* __restrict__ B, int E) {
    int tid = blockIdx.x * blockDim.x + threadIdx.x;
    int stride = gridDim.x * blockDim.x;
    for (int e = tid; e < E; e += stride) {
        int s = src[e];
        int d = dst[e];
        float2 v = A[s];
        atomicAdd(&B[2 * d], v.x);
        atomicAdd(&B[2 * d + 1], v.y);
    }
}

// K3: A = normalize(relu(B @ W_iter))   (fused matmul+relu+next-iter norm)
__global__ void wrelu_norm_kernel(const float2* __restrict__ B,
                                  float2* __restrict__ A,
                                  const float* __restrict__ W, int N) {
    int n = blockIdx.x * blockDim.x + threadIdx.x;
    if (n >= N) return;
    // W row-major [2][2]: y[k] = b0*W[0][k] + b1*W[1][k]
    float w00 = W[0], w01 = W[1], w10 = W[2], w11 = W[3];
    float2 b = B[n];
    float y0 = fmaxf(b.x * w00 + b.y * w10, 0.0f);
    float y1 = fmaxf(b.x * w01 + b.y * w11, 0.0f);
    float nm = sqrtf(y0 * y0 + y1 * y1);
    float inv = 1.0f / (nm + EPS);
    A[n] = make_float2(y0 * inv, y1 * inv);
}

// K4: out = sigmoid(relu(B @ W_iter) . final_weight)
__global__ void wrelu_sig_kernel(const float2* __restrict__ B,
                                 float* __restrict__ out,
                                 const float* __restrict__ W,
                                 const float* __restrict__ fw, int N) {
    int n = blockIdx.x * blockDim.x + threadIdx.x;
    if (n >= N) return;
    float w00 = W[0], w01 = W[1], w10 = W[2], w11 = W[3];
    float f0 = fw[0], f1 = fw[1];
    float2 b = B[n];
    float y0 = fmaxf(b.x * w00 + b.y * w10, 0.0f);
    float y1 = fmaxf(b.x * w01 + b.y * w11, 0.0f);
    float z = y0 * f0 + y1 * f1;
    out[n] = 1.0f / (1.0f + expf(-z));
}

extern "C" void kernel_launch(void* const* d_in, const int* in_sizes, int n_in,
                              void* d_out, int out_size, void* d_ws, size_t ws_size,
                              hipStream_t stream) {
    const float* x = (const float*)d_in[0];          // [N,2]
    const int* edge_index = (const int*)d_in[1];     // [2,E]
    const float* W = (const float*)d_in[2];          // [2,2,2]
    const float* fw = (const float*)d_in[3];         // [2]
    float* out = (float*)d_out;                      // [N]

    const int N = in_sizes[0] / 2;
    const int E = in_sizes[1] / 2;
    const int* src = edge_index;       // row 0 = message source j
    const int* dst = edge_index + E;   // row 1 = aggregation target i

    float* A = (float*)d_ws;                 // [N,2] normalized features
    float* B = A + (size_t)N * 2;            // [N,2] aggregation accumulator
    const size_t featBytes = (size_t)N * 2 * sizeof(float);

    const int BLK = 256;
    const int gridN = (N + BLK - 1) / BLK;
    const int gridE = 8192;  // grid-stride over edges

    // iter 0
    norm_input_kernel<<<gridN, BLK, 0, stream>>>((const float2*)x, (float2*)A, N);
    hipMemsetAsync(B, 0, featBytes, stream);
    scatter_kernel<<<gridE, BLK, 0, stream>>>(src, dst, (const float2*)A, B, E);
    wrelu_norm_kernel<<<gridN, BLK, 0, stream>>>((const float2*)B, (float2*)A, W, N);

    // iter 1
    hipMemsetAsync(B, 0, featBytes, stream);
    scatter_kernel<<<gridE, BLK, 0, stream>>>(src, dst, (const float2*)A, B, E);
    wrelu_sig_kernel<<<gridN, BLK, 0, stream>>>((const float2*)B, out, W + 4, fw, N);
}

// Round 2
// 1607.927 us; speedup vs baseline: 3.8632x; 3.8632x over previous
//
#include <hip/hip_runtime.h>
#include <hip/hip_bf16.h>
#include <math.h>

// Graph problem: 2 iterations of {row-L2-normalize -> scatter-add over edges ->
// 2x2 matmul + ReLU}, then sigmoid(x @ final_weight).
// N = 1M nodes (2 features), E = 32M edges.
//
// Strategy: global fp32 atomics were the wall (~20.7 G atomics/s, 64M per pass).
// Bin edges by dst bucket ONCE (reused by both iterations), then aggregate per
// bucket in LDS with ds_add_f32 and plain global stores.

#define EPS 1e-15f
#define SH_BITS 10
#define SH (1 << SH_BITS)   // nodes per bucket
#define NB_MAX 1024
#define CHUNK 32768         // edges per block in count/bin phases

// ---------------- node-wise kernels ----------------

__global__ void norm_input_kernel(const float2* __restrict__ x,
                                  float2* __restrict__ A, int N) {
    int n = blockIdx.x * blockDim.x + threadIdx.x;
    if (n >= N) return;
    float2 v = x[n];
    float nm = sqrtf(v.x * v.x + v.y * v.y);
    float inv = 1.0f / (nm + EPS);
    A[n] = make_float2(v.x * inv, v.y * inv);
}

__global__ void wrelu_norm_kernel(const float2* __restrict__ B,
                                  float2* __restrict__ A,
                                  const float* __restrict__ W, int N) {
    int n = blockIdx.x * blockDim.x + threadIdx.x;
    if (n >= N) return;
    float w00 = W[0], w01 = W[1], w10 = W[2], w11 = W[3];
    float2 b = B[n];
    float y0 = fmaxf(b.x * w00 + b.y * w10, 0.0f);
    float y1 = fmaxf(b.x * w01 + b.y * w11, 0.0f);
    float nm = sqrtf(y0 * y0 + y1 * y1);
    float inv = 1.0f / (nm + EPS);
    A[n] = make_float2(y0 * inv, y1 * inv);
}

__global__ void wrelu_sig_kernel(const float2* __restrict__ B,
                                 float* __restrict__ out,
                                 const float* __restrict__ W,
                                 const float* __restrict__ fw, int N) {
    int n = blockIdx.x * blockDim.x + threadIdx.x;
    if (n >= N) return;
    float w00 = W[0], w01 = W[1], w10 = W[2], w11 = W[3];
    float f0 = fw[0], f1 = fw[1];
    float2 b = B[n];
    float y0 = fmaxf(b.x * w00 + b.y * w10, 0.0f);
    float y1 = fmaxf(b.x * w01 + b.y * w11, 0.0f);
    float z = y0 * f0 + y1 * f1;
    out[n] = 1.0f / (1.0f + expf(-z));
}

// ---------------- binned-aggregation pipeline ----------------

// P0: per-bucket edge counts (LDS-privatized histogram)
__global__ void count_kernel(const int* __restrict__ dst, int E, int NB,
                             unsigned int* __restrict__ cnt) {
    __shared__ unsigned int h[NB_MAX];
    for (int i = threadIdx.x; i < NB; i += blockDim.x) h[i] = 0;
    __syncthreads();
    int e0 = blockIdx.x * CHUNK;
    int e1 = min(E, e0 + CHUNK);
    for (int e = e0 + threadIdx.x; e < e1; e += blockDim.x) {
        int b = dst[e] >> SH_BITS;
        atomicAdd(&h[b], 1u);
    }
    __syncthreads();
    for (int i = threadIdx.x; i < NB; i += blockDim.x)
        if (h[i]) atomicAdd(&cnt[i], h[i]);
}

// P1: exclusive scan of bucket counts (single block, blockDim == NB_MAX)
__global__ void scan_kernel(const unsigned int* __restrict__ cnt, int NB,
                            unsigned int* __restrict__ base,      // NB+1
                            unsigned int* __restrict__ cursor) {  // NB
    __shared__ unsigned int s[NB_MAX];
    int t = threadIdx.x;
    unsigned int v = (t < NB) ? cnt[t] : 0u;
    s[t] = v;
    __syncthreads();
    for (int off = 1; off < NB_MAX; off <<= 1) {
        unsigned int add = (t >= off) ? s[t - off] : 0u;
        __syncthreads();
        s[t] += add;
        __syncthreads();
    }
    if (t < NB) {
        unsigned int excl = s[t] - v;
        base[t] = excl;
        cursor[t] = excl;
        if (t == NB - 1) base[NB] = s[t];  // total == E
    }
}

// P2: scatter packed (dst_local<<20 | src) words into bucket-contiguous array
__global__ void bin_kernel(const int* __restrict__ src,
                           const int* __restrict__ dst, int E, int NB,
                           unsigned int* __restrict__ cursor,
                           unsigned int* __restrict__ bucketed) {
    __shared__ unsigned int h[NB_MAX];
    __shared__ unsigned int bb[NB_MAX];
    for (int i = threadIdx.x; i < NB; i += blockDim.x) h[i] = 0;
    __syncthreads();
    int e0 = blockIdx.x * CHUNK;
    int e1 = min(E, e0 + CHUNK);
    for (int e = e0 + threadIdx.x; e < e1; e += blockDim.x) {
        int b = dst[e] >> SH_BITS;
        atomicAdd(&h[b], 1u);
    }
    __syncthreads();
    for (int i = threadIdx.x; i < NB; i += blockDim.x) {
        unsigned int c = h[i];
        bb[i] = c ? atomicAdd(&cursor[i], c) : 0u;
        h[i] = 0;
    }
    __syncthreads();
    for (int e = e0 + threadIdx.x; e < e1; e += blockDim.x) {
        int d = dst[e];
        int b = d >> SH_BITS;
        unsigned int r = atomicAdd(&h[b], 1u);          // LDS rank
        unsigned int pos = bb[b] + r;
        unsigned int w = ((unsigned int)(d & (SH - 1)) << 20) |
                         (unsigned int)src[e];
        bucketed[pos] = w;
    }
}

// P3: per-bucket aggregation in LDS, plain stores to B (no global atomics)
__global__ void agg_kernel(const unsigned int* __restrict__ bucketed,
                           const unsigned int* __restrict__ base,
                           const float2* __restrict__ A,
                           float2* __restrict__ B, int N) {
    __shared__ float acc[SH * 2];
    int b = blockIdx.x;
    for (int i = threadIdx.x; i < SH * 2; i += blockDim.x) acc[i] = 0.0f;
    __syncthreads();
    unsigned int p0 = base[b], p1 = base[b + 1];
    for (unsigned int p = p0 + threadIdx.x; p < p1; p += blockDim.x) {
        unsigned int w = bucketed[p];
        int s = (int)(w & 0xFFFFFu);
        int dl = (int)(w >> 20);
        float2 v = A[s];
        atomicAdd(&acc[2 * dl], v.x);       // ds_add_f32
        atomicAdd(&acc[2 * dl + 1], v.y);
    }
    __syncthreads();
    int n0 = b << SH_BITS;
    for (int i = threadIdx.x; i < SH && n0 + i < N; i += blockDim.x)
        B[n0 + i] = make_float2(acc[2 * i], acc[2 * i + 1]);
}

// ---------------- fallback: direct global-atomic scatter ----------------

__global__ void scatter_kernel(const int* __restrict__ src,
                               const int* __restrict__ dst,
                               const float2* __restrict__ A,
                               float* __restrict__ B, int E) {
    int tid = blockIdx.x * blockDim.x + threadIdx.x;
    int stride = gridDim.x * blockDim.x;
    for (int e = tid; e < E; e += stride) {
        int s = src[e];
        int d = dst[e];
        float2 v = A[s];
#if defined(__HIP_DEVICE_COMPILE__)
        unsafeAtomicAdd(&B[2 * d], v.x);
        unsafeAtomicAdd(&B[2 * d + 1], v.y);
#else
        atomicAdd(&B[2 * d], v.x);
        atomicAdd(&B[2 * d + 1], v.y);
#endif
    }
}

extern "C" void kernel_launch(void* const* d_in, const int* in_sizes, int n_in,
                              void* d_out, int out_size, void* d_ws, size_t ws_size,
                              hipStream_t stream) {
    const float* x = (const float*)d_in[0];          // [N,2]
    const int* edge_index = (const int*)d_in[1];     // [2,E]
    const float* W = (const float*)d_in[2];          // [2,2,2]
    const float* fw = (const float*)d_in[3];         // [2]
    float* out = (float*)d_out;                      // [N]

    const int N = in_sizes[0] / 2;
    const int E = in_sizes[1] / 2;
    const int* src = edge_index;       // row 0 = message source j
    const int* dst = edge_index + E;   // row 1 = aggregation target i

    const int NB = (N + SH - 1) >> SH_BITS;          // 977 for N=1e6

    // workspace layout
    char* ws = (char*)d_ws;
    float* A = (float*)ws;                               // [N,2]
    float* B = A + (size_t)N * 2;                        // [N,2]
    unsigned int* bucketed = (unsigned int*)(B + (size_t)N * 2);  // [E]
    unsigned int* cnt    = bucketed + (size_t)E;         // [NB]
    unsigned int* base   = cnt + NB;                     // [NB+1]
    unsigned int* cursor = base + NB + 1;                // [NB]
    size_t need = (char*)(cursor + NB) - ws;

    const int BLK = 256;
    const int gridN = (N + BLK - 1) / BLK;

    norm_input_kernel<<<gridN, BLK, 0, stream>>>((const float2*)x, (float2*)A, N);

    if (ws_size >= need && NB <= NB_MAX) {
        const int gridC = (E + CHUNK - 1) / CHUNK;
        hipMemsetAsync(cnt, 0, (size_t)NB * sizeof(unsigned int), stream);
        count_kernel<<<gridC, BLK, 0, stream>>>(dst, E, NB, cnt);
        scan_kernel<<<1, NB_MAX, 0, stream>>>(cnt, NB, base, cursor);
        bin_kernel<<<gridC, BLK, 0, stream>>>(src, dst, E, NB, cursor, bucketed);

        // iter 0
        agg_kernel<<<NB, BLK, 0, stream>>>(bucketed, base, (const float2*)A,
                                           (float2*)B, N);
        wrelu_norm_kernel<<<gridN, BLK, 0, stream>>>((const float2*)B, (float2*)A, W, N);
        // iter 1
        agg_kernel<<<NB, BLK, 0, stream>>>(bucketed, base, (const float2*)A,
                                           (float2*)B, N);
        wrelu_sig_kernel<<<gridN, BLK, 0, stream>>>((const float2*)B, out, W + 4, fw, N);
    } else {
        // fallback: direct atomic scatter (native fp atomics)
        const size_t featBytes = (size_t)N * 2 * sizeof(float);
        const int gridE = 8192;
        hipMemsetAsync(B, 0, featBytes, stream);
        scatter_kernel<<<gridE, BLK, 0, stream>>>(src, dst, (const float2*)A, B, E);
        wrelu_norm_kernel<<<gridN, BLK, 0, stream>>>((const float2*)B, (float2*)A, W, N);
        hipMemsetAsync(B, 0, featBytes, stream);
        scatter_kernel<<<gridE, BLK, 0, stream>>>(src, dst, (const float2*)A, B, E);
        wrelu_sig_kernel<<<gridN, BLK, 0, stream>>>((const float2*)B, out, W + 4, fw, N);
    }
}

// Round 3
// 1064.799 us; speedup vs baseline: 5.8337x; 1.5101x over previous
//
#include <hip/hip_runtime.h>
#include <hip/hip_bf16.h>
#include <math.h>

// 2 iterations of {row-L2-normalize -> scatter-add over 32M edges -> 2x2 matmul
// + ReLU}, then sigmoid(x @ final_weight). N = 1M nodes, E = 32M edges.
//
// Pipeline: hist (per-block x per-bucket counts) -> colscan (exclusive scan over
// blocks, per bucket) -> base (bucket bases, 16B-aligned) -> bin (block-local
// LDS bucket-sort, coalesced run flush) -> 2x { agg (LDS accumulate per 4096-node
// bucket, uint4 + 4-way gather MLP) + fused matmul/relu/norm-or-sigmoid }.

#define EPS 1e-15f
#define SB_BITS 12
#define SB 4096              // nodes per bucket
#define NBK 256              // padded bucket count (real NB = ceil(1e6/4096) = 245)
#define CHUNK 4096           // edges per partition block
#define SCAN_BK 16           // buckets per colscan block

// ---------------- node-wise kernels ----------------

__global__ void norm_input_kernel(const float2* __restrict__ x,
                                  float2* __restrict__ A, int N) {
    int n = blockIdx.x * blockDim.x + threadIdx.x;
    if (n >= N) return;
    float2 v = x[n];
    float nm = sqrtf(v.x * v.x + v.y * v.y);
    float inv = 1.0f / (nm + EPS);
    A[n] = make_float2(v.x * inv, v.y * inv);
}

__global__ void wrelu_norm_kernel(const float2* __restrict__ B,
                                  float2* __restrict__ A,
                                  const float* __restrict__ W, int N) {
    int n = blockIdx.x * blockDim.x + threadIdx.x;
    if (n >= N) return;
    float w00 = W[0], w01 = W[1], w10 = W[2], w11 = W[3];
    float2 b = B[n];
    float y0 = fmaxf(b.x * w00 + b.y * w10, 0.0f);
    float y1 = fmaxf(b.x * w01 + b.y * w11, 0.0f);
    float nm = sqrtf(y0 * y0 + y1 * y1);
    float inv = 1.0f / (nm + EPS);
    A[n] = make_float2(y0 * inv, y1 * inv);
}

__global__ void wrelu_sig_kernel(const float2* __restrict__ B,
                                 float* __restrict__ out,
                                 const float* __restrict__ W,
                                 const float* __restrict__ fw, int N) {
    int n = blockIdx.x * blockDim.x + threadIdx.x;
    if (n >= N) return;
    float w00 = W[0], w01 = W[1], w10 = W[2], w11 = W[3];
    float f0 = fw[0], f1 = fw[1];
    float2 b = B[n];
    float y0 = fmaxf(b.x * w00 + b.y * w10, 0.0f);
    float y1 = fmaxf(b.x * w01 + b.y * w11, 0.0f);
    float z = y0 * f0 + y1 * f1;
    out[n] = 1.0f / (1.0f + expf(-z));
}

// ---------------- partition pipeline ----------------

// P0: per-(block,bucket) histogram, block-major H[blk][b] (coalesced writes)
__global__ void hist_kernel(const int* __restrict__ dst, int E,
                            unsigned int* __restrict__ H) {
    __shared__ unsigned int h[NBK];
    int t = threadIdx.x;
    if (t < NBK) h[t] = 0;
    __syncthreads();
    int e0 = blockIdx.x * CHUNK, e1 = min(E, e0 + CHUNK);
    for (int e = e0 + t; e < e1; e += 256)
        atomicAdd(&h[dst[e] >> SB_BITS], 1u);
    __syncthreads();
    unsigned int* row = H + (size_t)blockIdx.x * NBK;
    if (t < NBK) row[t] = h[t];
}

// P1: in-place exclusive scan of H along blocks, per bucket; totals -> T
__global__ void colscan_kernel(unsigned int* __restrict__ H, int gridC,
                               unsigned int* __restrict__ T) {
    __shared__ unsigned int tile[SCAN_BK][257];
    __shared__ unsigned int carry[SCAN_BK];
    int t = threadIdx.x;               // 256
    int b0 = blockIdx.x * SCAN_BK;
    if (t < SCAN_BK) carry[t] = 0;
    __syncthreads();
    int w = t >> 6, lane = t & 63;
    int rounds = (gridC + 255) / 256;
    for (int i = 0; i < rounds; ++i) {
        int blk = i * 256 + t;
        uint4 v0 = make_uint4(0,0,0,0), v1 = v0, v2 = v0, v3 = v0;
        if (blk < gridC) {
            const uint4* p = (const uint4*)(H + (size_t)blk * NBK + b0);
            v0 = p[0]; v1 = p[1]; v2 = p[2]; v3 = p[3];
        }
        tile[0][t]=v0.x;  tile[1][t]=v0.y;  tile[2][t]=v0.z;  tile[3][t]=v0.w;
        tile[4][t]=v1.x;  tile[5][t]=v1.y;  tile[6][t]=v1.z;  tile[7][t]=v1.w;
        tile[8][t]=v2.x;  tile[9][t]=v2.y;  tile[10][t]=v2.z; tile[11][t]=v2.w;
        tile[12][t]=v3.x; tile[13][t]=v3.y; tile[14][t]=v3.z; tile[15][t]=v3.w;
        __syncthreads();
        for (int c = w * 4; c < w * 4 + 4; ++c) {
            unsigned int cb = carry[c];
            unsigned int run = 0;
            for (int seg = 0; seg < 4; ++seg) {
                unsigned int x = tile[c][seg * 64 + lane];
                unsigned int inc = x;
                for (int off = 1; off < 64; off <<= 1) {
                    unsigned int y = __shfl_up(inc, off);
                    if (lane >= off) inc += y;
                }
                tile[c][seg * 64 + lane] = inc - x + run + cb;
                run += __shfl(inc, 63);
            }
            if (lane == 0) carry[c] = cb + run;
        }
        __syncthreads();
        if (blk < gridC) {
            v0 = make_uint4(tile[0][t],  tile[1][t],  tile[2][t],  tile[3][t]);
            v1 = make_uint4(tile[4][t],  tile[5][t],  tile[6][t],  tile[7][t]);
            v2 = make_uint4(tile[8][t],  tile[9][t],  tile[10][t], tile[11][t]);
            v3 = make_uint4(tile[12][t], tile[13][t], tile[14][t], tile[15][t]);
            uint4* p = (uint4*)(H + (size_t)blk * NBK + b0);
            p[0] = v0; p[1] = v1; p[2] = v2; p[3] = v3;
        }
        __syncthreads();
    }
    if (t < SCAN_BK) T[b0 + t] = carry[t];
}

// P2: bucket bases, each rounded to 4 words (16B) so agg can use uint4 loads
__global__ void base_kernel(const unsigned int* __restrict__ T,
                            unsigned int* __restrict__ base) {
    __shared__ unsigned int wp[4];
    int t = threadIdx.x;               // 256
    unsigned int v = (T[t] + 3u) & ~3u;
    int lane = t & 63, w = t >> 6;
    unsigned int inc = v;
    for (int off = 1; off < 64; off <<= 1) {
        unsigned int y = __shfl_up(inc, off);
        if (lane >= off) inc += y;
    }
    if (lane == 63) wp[w] = inc;
    __syncthreads();
    unsigned int add = 0;
    for (int j = 0; j < w; ++j) add += wp[j];
    base[t] = inc - v + add;
    if (t == 255) base[256] = inc + add;
}

// P3: block-local bucket sort in LDS, then coalesced run flush
__global__ void bin_kernel2(const int* __restrict__ src,
                            const int* __restrict__ dst, int E,
                            const unsigned int* __restrict__ H,
                            const unsigned int* __restrict__ base,
                            unsigned int* __restrict__ bucketed) {
    __shared__ unsigned int h[NBK], cur[NBK], gb[NBK];
    __shared__ unsigned int stage[CHUNK];
    __shared__ unsigned char sb[CHUNK];
    __shared__ unsigned int wp[4];
    int t = threadIdx.x;               // 256
    int e0 = blockIdx.x * CHUNK, e1 = min(E, e0 + CHUNK), n = e1 - e0;
    if (t < NBK) h[t] = 0;
    __syncthreads();
    for (int e = e0 + t; e < e1; e += 256)
        atomicAdd(&h[dst[e] >> SB_BITS], 1u);
    __syncthreads();
    // exclusive scan h -> cur (256 entries, 1 per thread)
    unsigned int v = h[t];
    int lane = t & 63, w = t >> 6;
    unsigned int inc = v;
    for (int off = 1; off < 64; off <<= 1) {
        unsigned int y = __shfl_up(inc, off);
        if (lane >= off) inc += y;
    }
    if (lane == 63) wp[w] = inc;
    __syncthreads();
    unsigned int add = 0;
    for (int j = 0; j < w; ++j) add += wp[j];
    cur[t] = inc - v + add;
    // global base for this block's segment of each bucket
    gb[t] = base[t] + H[(size_t)blockIdx.x * NBK + t];
    __syncthreads();
    // rank + stage (bucket-sorted within block)
    for (int e = e0 + t; e < e1; e += 256) {
        int d = dst[e];
        int b = d >> SB_BITS;
        unsigned int r = atomicAdd(&cur[b], 1u);
        stage[r] = ((unsigned int)(d & (SB - 1)) << 20) | (unsigned int)src[e];
        sb[r] = (unsigned char)b;
    }
    __syncthreads();
    // flush: lane-consecutive i -> consecutive global positions within runs
    for (int i = t; i < n; i += 256) {
        int b = sb[i];
        unsigned int lb = cur[b] - h[b];   // original local base
        bucketed[gb[b] + (unsigned int)i - lb] = stage[i];
    }
}

// P4: per-bucket aggregation in LDS (32 KB), 4-way gather MLP, plain stores
__global__ void agg_kernel2(const unsigned int* __restrict__ bucketed,
                            const unsigned int* __restrict__ base,
                            const unsigned int* __restrict__ T,
                            const float2* __restrict__ A,
                            float2* __restrict__ B, int N) {
    __shared__ float acc[SB * 2];      // 32 KB
    int b = blockIdx.x;
    int t = threadIdx.x;               // 1024
    for (int i = t; i < SB * 2; i += 1024) acc[i] = 0.0f;
    __syncthreads();
    unsigned int p0 = base[b];
    unsigned int cnt = T[b];
    for (unsigned int q = 4u * (unsigned int)t; q < cnt; q += 4096u) {
        uint4 w4 = *(const uint4*)(bucketed + p0 + q);
        unsigned int wv[4] = {w4.x, w4.y, w4.z, w4.w};
        float2 vv[4];
        #pragma unroll
        for (int j = 0; j < 4; ++j) {
            unsigned int s = wv[j] & 0xFFFFFu;
            s = min(s, (unsigned int)(N - 1));
            vv[j] = A[s];              // 4 independent gathers in flight
        }
        #pragma unroll
        for (int j = 0; j < 4; ++j) {
            if (q + j < cnt) {
                int dl = (int)(wv[j] >> 20);
                atomicAdd(&acc[2 * dl], vv[j].x);      // ds_add_f32
                atomicAdd(&acc[2 * dl + 1], vv[j].y);
            }
        }
    }
    __syncthreads();
    int n0 = b << SB_BITS;
    for (int i = t; i < SB && n0 + i < N; i += 1024)
        B[n0 + i] = make_float2(acc[2 * i], acc[2 * i + 1]);
}

// ---------------- fallback: direct global-atomic scatter ----------------

__global__ void scatter_kernel(const int* __restrict__ src,
                               const int* __restrict__ dst,
                               const float2* __restrict__ A,
                               float* __restrict__ B, int E) {
    int tid = blockIdx.x * blockDim.x + threadIdx.x;
    int stride = gridDim.x * blockDim.x;
    for (int e = tid; e < E; e += stride) {
        int s = src[e];
        int d = dst[e];
        float2 v = A[s];
        atomicAdd(&B[2 * d], v.x);
        atomicAdd(&B[2 * d + 1], v.y);
    }
}

extern "C" void kernel_launch(void* const* d_in, const int* in_sizes, int n_in,
                              void* d_out, int out_size, void* d_ws, size_t ws_size,
                              hipStream_t stream) {
    const float* x = (const float*)d_in[0];          // [N,2]
    const int* edge_index = (const int*)d_in[1];     // [2,E]
    const float* W = (const float*)d_in[2];          // [2,2,2]
    const float* fw = (const float*)d_in[3];         // [2]
    float* out = (float*)d_out;                      // [N]

    const int N = in_sizes[0] / 2;
    const int E = in_sizes[1] / 2;
    const int* src = edge_index;       // row 0 = message source j
    const int* dst = edge_index + E;   // row 1 = aggregation target i

    const int NB = (N + SB - 1) >> SB_BITS;          // 245 for N=1e6
    const int gridC = (E + CHUNK - 1) / CHUNK;       // 7813

    // workspace layout: A | U = max(B, H) | bucketed | T | base
    char* ws = (char*)d_ws;
    float* A = (float*)ws;                                   // [N,2]
    size_t aBytes = (size_t)N * 2 * sizeof(float);
    size_t bBytes = (size_t)N * 2 * sizeof(float);
    size_t hBytes = (size_t)gridC * NBK * sizeof(unsigned int);
    size_t uBytes = (bBytes > hBytes ? bBytes : hBytes);
    float* B = (float*)(ws + aBytes);
    unsigned int* H = (unsigned int*)(ws + aBytes);          // aliases B (dead until agg)
    unsigned int* bucketed = (unsigned int*)(ws + aBytes + uBytes);  // [E + 1024]
    unsigned int* T    = bucketed + (size_t)E + 1024;        // [NBK]
    unsigned int* base = T + NBK;                            // [NBK+1]
    size_t need = (char*)(base + NBK + 1) - ws;

    const int BLK = 256;
    const int gridN = (N + BLK - 1) / BLK;

    norm_input_kernel<<<gridN, BLK, 0, stream>>>((const float2*)x, (float2*)A, N);

    if (ws_size >= need && NB <= NBK && N <= (1 << 20)) {
        hist_kernel<<<gridC, 256, 0, stream>>>(dst, E, H);
        colscan_kernel<<<NBK / SCAN_BK, 256, 0, stream>>>(H, gridC, T);
        base_kernel<<<1, 256, 0, stream>>>(T, base);
        bin_kernel2<<<gridC, 256, 0, stream>>>(src, dst, E, H, base, bucketed);

        // iter 0
        agg_kernel2<<<NB, 1024, 0, stream>>>(bucketed, base, T, (const float2*)A,
                                             (float2*)B, N);
        wrelu_norm_kernel<<<gridN, BLK, 0, stream>>>((const float2*)B, (float2*)A, W, N);
        // iter 1
        agg_kernel2<<<NB, 1024, 0, stream>>>(bucketed, base, T, (const float2*)A,
                                             (float2*)B, N);
        wrelu_sig_kernel<<<gridN, BLK, 0, stream>>>((const float2*)B, out, W + 4, fw, N);
    } else {
        // fallback: direct atomic scatter
        const size_t featBytes = (size_t)N * 2 * sizeof(float);
        const int gridE = 8192;
        hipMemsetAsync(B, 0, featBytes, stream);
        scatter_kernel<<<gridE, BLK, 0, stream>>>(src, dst, (const float2*)A, (float*)B, E);
        wrelu_norm_kernel<<<gridN, BLK, 0, stream>>>((const float2*)B, (float2*)A, W, N);
        hipMemsetAsync(B, 0, featBytes, stream);
        scatter_kernel<<<gridE, BLK, 0, stream>>>(src, dst, (const float2*)A, (float*)B, E);
        wrelu_sig_kernel<<<gridN, BLK, 0, stream>>>((const float2*)B, out, W + 4, fw, N);
    }
}

// Round 4
// 951.723 us; speedup vs baseline: 6.5268x; 1.1188x over previous
//
#include <hip/hip_runtime.h>
#include <hip/hip_bf16.h>
#include <hip/hip_fp16.h>
#include <math.h>

// 2 iterations of {row-L2-normalize -> scatter-add over 32M edges -> 2x2 matmul
// + ReLU}, then sigmoid(x @ final_weight). N = 1M nodes, E = 32M edges.
//
// Pipeline: hist -> colscan -> base -> bin (block-local LDS bucket sort,
// coalesced flush) -> agg x2 (LDS accumulate per 4096-node dst bucket).
// Partition key = (dst_bucket << 1) | (src >= N/2): agg processes lo-src then
// hi-src sub-streams so the random gather table slice (4 MB) stays resident in
// each XCD's 4 MB L2 (all 245 agg blocks co-resident -> lockstep phases).
// Iter-1 gathers f32 (sign-critical), iter-2 gathers half2 (exact for this W).

#define EPS 1e-15f
#define SB_BITS 12
#define SB 4096              // dst nodes per bucket
#define NBK 512              // padded key count (real = 2 * 245 = 490)
#define CHUNK 8192           // edges per partition block
#define SCAN_BK 8            // keys per colscan block

typedef unsigned int u32;
typedef unsigned int u32x4 __attribute__((ext_vector_type(4)));

// ---------------- node-wise kernels ----------------

__global__ void norm_input_kernel(const float2* __restrict__ x,
                                  float2* __restrict__ A, int N) {
    int n = blockIdx.x * blockDim.x + threadIdx.x;
    if (n >= N) return;
    float2 v = x[n];
    float nm = sqrtf(v.x * v.x + v.y * v.y);
    float inv = 1.0f / (nm + EPS);
    A[n] = make_float2(v.x * inv, v.y * inv);
}

// iter-1 matmul+relu+normalize, output as half2 (exact for (1,0)/(0,1)/(0,0))
__global__ void wrelu_half_kernel(const float2* __restrict__ B,
                                  u32* __restrict__ A1,
                                  const float* __restrict__ W, int N) {
    int n = blockIdx.x * blockDim.x + threadIdx.x;
    if (n >= N) return;
    float w00 = W[0], w01 = W[1], w10 = W[2], w11 = W[3];
    float2 b = B[n];
    float y0 = fmaxf(b.x * w00 + b.y * w10, 0.0f);
    float y1 = fmaxf(b.x * w01 + b.y * w11, 0.0f);
    float nm = sqrtf(y0 * y0 + y1 * y1);
    float inv = 1.0f / (nm + EPS);
    __half2 h = __floats2half2_rn(y0 * inv, y1 * inv);
    A1[n] = __builtin_bit_cast(u32, h);
}

__global__ void wrelu_sig_kernel(const float2* __restrict__ B,
                                 float* __restrict__ out,
                                 const float* __restrict__ W,
                                 const float* __restrict__ fw, int N) {
    int n = blockIdx.x * blockDim.x + threadIdx.x;
    if (n >= N) return;
    float w00 = W[0], w01 = W[1], w10 = W[2], w11 = W[3];
    float f0 = fw[0], f1 = fw[1];
    float2 b = B[n];
    float y0 = fmaxf(b.x * w00 + b.y * w10, 0.0f);
    float y1 = fmaxf(b.x * w01 + b.y * w11, 0.0f);
    float z = y0 * f0 + y1 * f1;
    out[n] = 1.0f / (1.0f + expf(-z));
}

// ---------------- partition pipeline ----------------

// P0: per-(block,key) histogram, block-major H[blk][key]
__global__ __launch_bounds__(512) void hist_kernel(const int* __restrict__ src,
                                                   const int* __restrict__ dst,
                                                   int E, int N2,
                                                   u32* __restrict__ H) {
    __shared__ u32 h[NBK];
    int t = threadIdx.x;                // 512
    h[t] = 0;
    __syncthreads();
    int e0 = blockIdx.x * CHUNK, e1 = min(E, e0 + CHUNK);
    for (int e = e0 + t; e < e1; e += 512) {
        int key = ((dst[e] >> SB_BITS) << 1) | (src[e] >= N2 ? 1 : 0);
        atomicAdd(&h[key], 1u);
    }
    __syncthreads();
    H[(size_t)blockIdx.x * NBK + t] = h[t];
}

// P1: in-place exclusive scan of H along blocks, per key; totals -> T
__global__ void colscan_kernel(u32* __restrict__ H, int gridC,
                               u32* __restrict__ T) {
    __shared__ u32 tile[SCAN_BK][257];
    __shared__ u32 carry[SCAN_BK];
    int t = threadIdx.x;                // 256
    int b0 = blockIdx.x * SCAN_BK;
    if (t < SCAN_BK) carry[t] = 0;
    __syncthreads();
    int w = t >> 6, lane = t & 63;
    int rounds = (gridC + 255) / 256;
    for (int i = 0; i < rounds; ++i) {
        int blk = i * 256 + t;
        uint4 v0 = make_uint4(0, 0, 0, 0), v1 = v0;
        if (blk < gridC) {
            const uint4* p = (const uint4*)(H + (size_t)blk * NBK + b0);
            v0 = p[0]; v1 = p[1];
        }
        tile[0][t] = v0.x; tile[1][t] = v0.y; tile[2][t] = v0.z; tile[3][t] = v0.w;
        tile[4][t] = v1.x; tile[5][t] = v1.y; tile[6][t] = v1.z; tile[7][t] = v1.w;
        __syncthreads();
        for (int c = w * 2; c < w * 2 + 2; ++c) {
            u32 cb = carry[c];
            u32 run = 0;
            for (int seg = 0; seg < 4; ++seg) {
                u32 x = tile[c][seg * 64 + lane];
                u32 inc = x;
                for (int off = 1; off < 64; off <<= 1) {
                    u32 y = __shfl_up(inc, off);
                    if (lane >= off) inc += y;
                }
                tile[c][seg * 64 + lane] = inc - x + run + cb;
                run += __shfl(inc, 63);
            }
            if (lane == 0) carry[c] = cb + run;
        }
        __syncthreads();
        if (blk < gridC) {
            v0 = make_uint4(tile[0][t], tile[1][t], tile[2][t], tile[3][t]);
            v1 = make_uint4(tile[4][t], tile[5][t], tile[6][t], tile[7][t]);
            uint4* p = (uint4*)(H + (size_t)blk * NBK + b0);
            p[0] = v0; p[1] = v1;
        }
        __syncthreads();
    }
    if (t < SCAN_BK) T[b0 + t] = carry[t];
}

// P2: key bases, rounded to 4 words (16B) for uint4 agg loads
__global__ __launch_bounds__(512) void base_kernel(const u32* __restrict__ T,
                                                   u32* __restrict__ base) {
    __shared__ u32 wp[8];
    int t = threadIdx.x;                // 512
    u32 v = (T[t] + 3u) & ~3u;
    int lane = t & 63, w = t >> 6;
    u32 inc = v;
    for (int off = 1; off < 64; off <<= 1) {
        u32 y = __shfl_up(inc, off);
        if (lane >= off) inc += y;
    }
    if (lane == 63) wp[w] = inc;
    __syncthreads();
    u32 add = 0;
    for (int j = 0; j < w; ++j) add += wp[j];
    base[t] = inc - v + add;
    if (t == 511) base[512] = inc + add;
}

// P3: block-local key sort in LDS, then coalesced run flush
__global__ __launch_bounds__(512) void bin_kernel3(const int* __restrict__ src,
                                                   const int* __restrict__ dst,
                                                   int E, int N2,
                                                   const u32* __restrict__ H,
                                                   const u32* __restrict__ base,
                                                   u32* __restrict__ bucketed) {
    __shared__ u32 h[NBK], cur[NBK], gb[NBK];
    __shared__ u32 stage[CHUNK];          // 32 KB
    __shared__ unsigned char sb[CHUNK];   // 8 KB (dst bucket only)
    __shared__ u32 wp[8];
    int t = threadIdx.x;                  // 512
    int e0 = blockIdx.x * CHUNK, e1 = min(E, e0 + CHUNK), n = e1 - e0;
    h[t] = 0;
    __syncthreads();
    for (int e = e0 + t; e < e1; e += 512) {
        int key = ((dst[e] >> SB_BITS) << 1) | (src[e] >= N2 ? 1 : 0);
        atomicAdd(&h[key], 1u);
    }
    __syncthreads();
    // exclusive scan h -> cur (512 entries, 1/thread)
    u32 v = h[t];
    int lane = t & 63, w = t >> 6;
    u32 inc = v;
    for (int off = 1; off < 64; off <<= 1) {
        u32 y = __shfl_up(inc, off);
        if (lane >= off) inc += y;
    }
    if (lane == 63) wp[w] = inc;
    __syncthreads();
    u32 add = 0;
    for (int j = 0; j < w; ++j) add += wp[j];
    cur[t] = inc - v + add;
    gb[t] = base[t] + H[(size_t)blockIdx.x * NBK + t];
    __syncthreads();
    // rank + stage (key-sorted within block)
    for (int e = e0 + t; e < e1; e += 512) {
        int d = dst[e];
        int s = src[e];
        int key = ((d >> SB_BITS) << 1) | (s >= N2 ? 1 : 0);
        u32 r = atomicAdd(&cur[key], 1u);
        stage[r] = ((u32)(d & (SB - 1)) << 20) | (u32)s;
        sb[r] = (unsigned char)(d >> SB_BITS);
    }
    __syncthreads();
    // flush: consecutive i -> consecutive global positions within runs
    for (int i = t; i < n; i += 512) {
        int k = ((int)sb[i] << 1) | ((stage[i] & 0xFFFFFu) >= (u32)N2 ? 1 : 0);
        u32 lb = cur[k] - h[k];
        bucketed[gb[k] + (u32)i - lb] = stage[i];
    }
}

// P4: per-dst-bucket aggregation; lo-src phase then hi-src phase
template <int MODE>   // 0: f32 float2 table, 1: half2 table
__global__ __launch_bounds__(1024) void agg_kernel3(
        const u32* __restrict__ bucketed,
        const u32* __restrict__ base,
        const u32* __restrict__ T,
        const void* __restrict__ tab,
        float2* __restrict__ B, int N) {
    __shared__ float acc[SB * 2];         // 32 KB
    int b = blockIdx.x, t = threadIdx.x;  // 1024
    for (int i = t; i < SB * 2; i += 1024) acc[i] = 0.0f;
    __syncthreads();
    const float2* Af = (const float2*)tab;
    const u32* Ah = (const u32*)tab;
    #pragma unroll
    for (int half = 0; half < 2; ++half) {
        int k = 2 * b + half;
        u32 p0 = base[k], cnt = T[k];
        for (u32 q = 8u * (u32)t; q < cnt; q += 8192u) {
            const u32x4* p = (const u32x4*)(bucketed + p0 + q);
            u32x4 wa = __builtin_nontemporal_load(p);
            u32x4 wb = __builtin_nontemporal_load(p + 1);
            u32 wv[8] = {wa[0], wa[1], wa[2], wa[3], wb[0], wb[1], wb[2], wb[3]};
            float2 vv[8];
            #pragma unroll
            for (int j = 0; j < 8; ++j) {
                u32 s = wv[j] & 0xFFFFFu;
                s = min(s, (u32)(N - 1));
                if (MODE == 0) {
                    vv[j] = Af[s];
                } else {
                    u32 hw = Ah[s];
                    __half2 h2 = __builtin_bit_cast(__half2, hw);
                    vv[j] = __half22float2(h2);
                }
            }
            #pragma unroll
            for (int j = 0; j < 8; ++j) {
                if (q + j < cnt) {
                    int dl = (int)(wv[j] >> 20);
                    atomicAdd(&acc[2 * dl], vv[j].x);       // ds_add_f32
                    atomicAdd(&acc[2 * dl + 1], vv[j].y);
                }
            }
        }
    }
    __syncthreads();
    int n0 = b << SB_BITS;
    for (int i = t; i < SB && n0 + i < N; i += 1024)
        B[n0 + i] = make_float2(acc[2 * i], acc[2 * i + 1]);
}

// ---------------- fallback: direct global-atomic scatter ----------------

__global__ void wrelu_norm_kernel(const float2* __restrict__ B,
                                  float2* __restrict__ A,
                                  const float* __restrict__ W, int N) {
    int n = blockIdx.x * blockDim.x + threadIdx.x;
    if (n >= N) return;
    float w00 = W[0], w01 = W[1], w10 = W[2], w11 = W[3];
    float2 b = B[n];
    float y0 = fmaxf(b.x * w00 + b.y * w10, 0.0f);
    float y1 = fmaxf(b.x * w01 + b.y * w11, 0.0f);
    float nm = sqrtf(y0 * y0 + y1 * y1);
    float inv = 1.0f / (nm + EPS);
    A[n] = make_float2(y0 * inv, y1 * inv);
}

__global__ void scatter_kernel(const int* __restrict__ src,
                               const int* __restrict__ dst,
                               const float2* __restrict__ A,
                               float* __restrict__ B, int E) {
    int tid = blockIdx.x * blockDim.x + threadIdx.x;
    int stride = gridDim.x * blockDim.x;
    for (int e = tid; e < E; e += stride) {
        int s = src[e];
        int d = dst[e];
        float2 v = A[s];
        atomicAdd(&B[2 * d], v.x);
        atomicAdd(&B[2 * d + 1], v.y);
    }
}

extern "C" void kernel_launch(void* const* d_in, const int* in_sizes, int n_in,
                              void* d_out, int out_size, void* d_ws, size_t ws_size,
                              hipStream_t stream) {
    const float* x = (const float*)d_in[0];          // [N,2]
    const int* edge_index = (const int*)d_in[1];     // [2,E]
    const float* W = (const float*)d_in[2];          // [2,2,2]
    const float* fw = (const float*)d_in[3];         // [2]
    float* out = (float*)d_out;                      // [N]

    const int N = in_sizes[0] / 2;
    const int E = in_sizes[1] / 2;
    const int* src = edge_index;       // row 0 = message source j
    const int* dst = edge_index + E;   // row 1 = aggregation target i

    const int NB = (N + SB - 1) >> SB_BITS;          // 245
    const int N2 = N >> 1;
    const int gridC = (E + CHUNK - 1) / CHUNK;       // 3907

    // workspace: A0 (f32 table, aliased by A1 half2 table) | U = max(B, H) |
    //            bucketed | T | base
    char* ws = (char*)d_ws;
    float* A0 = (float*)ws;                                  // [N,2] f32
    u32* A1 = (u32*)ws;                                      // [N] half2 (aliases A0)
    size_t aBytes = (size_t)N * 2 * sizeof(float);
    size_t bBytes = (size_t)N * 2 * sizeof(float);
    size_t hBytes = (size_t)gridC * NBK * sizeof(u32);
    size_t uBytes = (bBytes > hBytes ? bBytes : hBytes);
    float* B = (float*)(ws + aBytes);
    u32* H = (u32*)(ws + aBytes);                            // aliases B
    u32* bucketed = (u32*)(ws + aBytes + uBytes);            // [E + 2048]
    u32* T = bucketed + (size_t)E + 2048;                    // [NBK]
    u32* base = T + NBK;                                     // [NBK+1]
    size_t need = (char*)(base + NBK + 1) - ws;

    const int BLK = 256;
    const int gridN = (N + BLK - 1) / BLK;

    norm_input_kernel<<<gridN, BLK, 0, stream>>>((const float2*)x, (float2*)A0, N);

    if (ws_size >= need && 2 * NB <= NBK && N <= (1 << 20)) {
        hist_kernel<<<gridC, 512, 0, stream>>>(src, dst, E, N2, H);
        colscan_kernel<<<NBK / SCAN_BK, 256, 0, stream>>>(H, gridC, T);
        base_kernel<<<1, 512, 0, stream>>>(T, base);
        bin_kernel3<<<gridC, 512, 0, stream>>>(src, dst, E, N2, H, base, bucketed);

        // iter 0: gather f32 (sign-critical precision)
        agg_kernel3<0><<<NB, 1024, 0, stream>>>(bucketed, base, T, A0,
                                                (float2*)B, N);
        wrelu_half_kernel<<<gridN, BLK, 0, stream>>>((const float2*)B, A1, W, N);
        // iter 1: gather half2 (exact for relu+normalize output of this W)
        agg_kernel3<1><<<NB, 1024, 0, stream>>>(bucketed, base, T, A1,
                                                (float2*)B, N);
        wrelu_sig_kernel<<<gridN, BLK, 0, stream>>>((const float2*)B, out, W + 4, fw, N);
    } else {
        // fallback: direct atomic scatter
        const size_t featBytes = (size_t)N * 2 * sizeof(float);
        const int gridE = 8192;
        hipMemsetAsync(B, 0, featBytes, stream);
        scatter_kernel<<<gridE, BLK, 0, stream>>>(src, dst, (const float2*)A0, (float*)B, E);
        wrelu_norm_kernel<<<gridN, BLK, 0, stream>>>((const float2*)B, (float2*)A0, W, N);
        hipMemsetAsync(B, 0, featBytes, stream);
        scatter_kernel<<<gridE, BLK, 0, stream>>>(src, dst, (const float2*)A0, (float*)B, E);
        wrelu_sig_kernel<<<gridN, BLK, 0, stream>>>((const float2*)B, out, W + 4, fw, N);
    }
}